// Round 4
// baseline (278.863 us; speedup 1.0000x reference)
//
#include <hip/hip_runtime.h>

// CCE loss reduction: out[0] = -sum(input * log(target + 1e-8)) / B
// B = 262144, C = 128, f32. 268 MB read-once -> memory-bound, ~43 us floor.
// R1: VGPR=12, 2 loads in flight/wave -> 104 us (2.58 TB/s).
// R2: source-level 4x unroll; compiler re-serialized it (VGPR=32) -> no change.
// R3: macro param/member-name collision -> compile fail. R4 = R3 with a
//     __device__ function instead of the macro.
//     Force MLP: launch_bounds(256,2) (VGPR cap 256), static ping-pong
//     pipeline (16 iters known at compile time), sched_barrier(0) after each
//     8-load cluster so the scheduler cannot sink loads below compute.

constexpr int BLOCK = 256;
constexpr int GRID  = 2048;   // 8 blocks/CU x 256 CUs
constexpr int PF    = 4;      // float4-pairs per batch = 8 dwordx4 loads
constexpr int ITERS = 16;     // 8.4M float4 / (GRID*BLOCK) = 16, exact

__device__ __forceinline__ void accum(const float4& u, const float4& v,
                                      float& a0, float& a1) {
  a0 += u.x * __logf(v.x + 1e-8f);
  a1 += u.y * __logf(v.y + 1e-8f);
  a0 += u.z * __logf(v.z + 1e-8f);
  a1 += u.w * __logf(v.w + 1e-8f);
}

__global__ __launch_bounds__(BLOCK, 2) void cce_reduce_kernel(
    const float* __restrict__ inp, const float* __restrict__ tgt,
    float* __restrict__ out, int n4, float neg_inv_b) {
  const float4* __restrict__ in4 = reinterpret_cast<const float4*>(inp);
  const float4* __restrict__ tg4 = reinterpret_cast<const float4*>(tgt);

  const int tid    = blockIdx.x * BLOCK + threadIdx.x;
  const int stride = GRID * BLOCK;

  float a0 = 0.0f, a1 = 0.0f;

  if (n4 == stride * ITERS) {
    // Fully static pipelined path (the benched shape).
    float4 xa[PF], ya[PF], xb[PF], yb[PF];

    const int i0 = tid;
    #pragma unroll
    for (int j = 0; j < PF; ++j) {
      xa[j] = in4[i0 + j * stride];
      ya[j] = tg4[i0 + j * stride];
    }
    __builtin_amdgcn_sched_barrier(0);  // batch0 loads stay up here

    const int i1 = i0 + PF * stride;
    #pragma unroll
    for (int j = 0; j < PF; ++j) {
      xb[j] = in4[i1 + j * stride];
      yb[j] = tg4[i1 + j * stride];
    }
    __builtin_amdgcn_sched_barrier(0);  // batch1 issued before batch0 compute
    #pragma unroll
    for (int j = 0; j < PF; ++j) accum(xa[j], ya[j], a0, a1);

    const int i2 = i1 + PF * stride;
    #pragma unroll
    for (int j = 0; j < PF; ++j) {
      xa[j] = in4[i2 + j * stride];
      ya[j] = tg4[i2 + j * stride];
    }
    __builtin_amdgcn_sched_barrier(0);
    #pragma unroll
    for (int j = 0; j < PF; ++j) accum(xb[j], yb[j], a0, a1);

    const int i3 = i2 + PF * stride;
    #pragma unroll
    for (int j = 0; j < PF; ++j) {
      xb[j] = in4[i3 + j * stride];
      yb[j] = tg4[i3 + j * stride];
    }
    __builtin_amdgcn_sched_barrier(0);
    #pragma unroll
    for (int j = 0; j < PF; ++j) accum(xa[j], ya[j], a0, a1);

    #pragma unroll
    for (int j = 0; j < PF; ++j) accum(xb[j], yb[j], a0, a1);
  } else {
    // Generic fallback (not taken for the benched shape).
    for (int i = tid; i < n4; i += stride) {
      float4 u = in4[i];
      float4 v = tg4[i];
      accum(u, v, a0, a1);
    }
  }

  float acc = a0 + a1;

  // wave-64 shuffle reduction
  #pragma unroll
  for (int off = 32; off > 0; off >>= 1)
    acc += __shfl_down(acc, off, 64);

  __shared__ float s[BLOCK / 64];
  const int lane = threadIdx.x & 63;
  const int wave = threadIdx.x >> 6;
  if (lane == 0) s[wave] = acc;
  __syncthreads();

  if (threadIdx.x == 0) {
    float t = 0.0f;
    #pragma unroll
    for (int w = 0; w < BLOCK / 64; ++w) t += s[w];
    atomicAdd(out, t * neg_inv_b);  // one device-scope atomic per block
  }
}

extern "C" void kernel_launch(void* const* d_in, const int* in_sizes, int n_in,
                              void* d_out, int out_size, void* d_ws, size_t ws_size,
                              hipStream_t stream) {
  const float* inp = reinterpret_cast<const float*>(d_in[0]);
  const float* tgt = reinterpret_cast<const float*>(d_in[1]);
  float* out = reinterpret_cast<float*>(d_out);

  const long long n = (long long)in_sizes[0];  // 262144 * 128
  const int n4 = (int)(n / 4);
  const long long B = 262144;                  // rows, per reference
  const float neg_inv_b = -1.0f / (float)B;

  // d_out is re-poisoned to 0xAA before every timed launch -> zero it here.
  (void)hipMemsetAsync(d_out, 0, out_size * sizeof(float), stream);

  cce_reduce_kernel<<<GRID, BLOCK, 0, stream>>>(inp, tgt, out, n4, neg_inv_b);
}